// Round 2
// baseline (1341.053 us; speedup 1.0000x reference)
//
#include <hip/hip_runtime.h>
#include <hip/hip_bf16.h>

typedef __attribute__((ext_vector_type(8))) short short8;
typedef __attribute__((ext_vector_type(4))) float f32x4;
typedef unsigned short u16;

#define NB   4096
#define TT   200
#define DS   32
#define DA   8
#define HH   128
#define HP   136
#define XP   72
#define BB   16
#define NTHR 512

#define OW_R 0
#define OW_Z 33024
#define OW_H 66048
#define OB_R 99072
#define OB_Z 99328
#define OB_H 99584
#define OTW  99840
#define OWIH 100096
#define OWHH 124672
#define OBIH 173824
#define OBHH 174208
#define ODW  174592
#define ODB  178688
#define NPK  178720
#define OFF2 16512
#define HIDOFF ((size_t)NB * TT * DS)   // element offset of hid inside d_out

__device__ __forceinline__ float bf2f(u16 u){
  union { unsigned int i; float f; } v; v.i = ((unsigned int)u) << 16; return v.f;
}
__device__ __forceinline__ u16 f2bf(float f){
  __hip_bfloat16 h = __float2bfloat16(f);
  return *reinterpret_cast<u16*>(&h);
}
__device__ __forceinline__ float sigm(float x){
  return __builtin_amdgcn_rcpf(1.f + __expf(-x));
}
__device__ __forceinline__ float tanh_(float x){
  return 1.f - 2.f * __builtin_amdgcn_rcpf(1.f + __expf(2.f * x));
}
__device__ __forceinline__ float scrub(float x){
  return fminf(8.f, fmaxf(-8.f, x));
}

__global__ void detect_kernel(const void* t_in, int* ws_flag){
  int lane = threadIdx.x;
  u16 v = ((const u16*)t_in)[2 * lane];
  float f = bf2f(v);
  bool ok = (f >= 0.0009765625f) && (f < 1.0f);
  unsigned long long m = __ballot(ok);
  if (lane == 0) ws_flag[0] = (__popcll(m) < 32) ? 1 : 0;   // 1 => fp32
}

__global__ void conv_kernel(const void* Wr, const void* Wz, const void* Wh,
                            const void* br, const void* bz, const void* bh,
                            const void* tw, const void* Wih, const void* Whh,
                            const void* bih, const void* bhh,
                            const void* dW, const void* db_, void* ws){
  const int flag = *(const int*)ws;
  u16* dst = (u16*)ws + 8;
  int i = blockIdx.x * 256 + threadIdx.x;
  if (i >= NPK) return;
  auto cv = [&](const void* p, int li) -> u16 {
    if (flag) return f2bf(((const float*)p)[li]);
    return ((const u16*)p)[li];
  };
  u16 v;
  if      (i < OW_Z) v = cv(Wr,  i - OW_R);
  else if (i < OW_H) v = cv(Wz,  i - OW_Z);
  else if (i < OB_R) v = cv(Wh,  i - OW_H);
  else if (i < OB_Z) v = cv(br,  i - OB_R);
  else if (i < OB_H) v = cv(bz,  i - OB_Z);
  else if (i < OTW)  v = cv(bh,  i - OB_H);
  else if (i < OWIH) v = cv(tw,  i - OTW);
  else if (i < OWHH) { int li = i - OWIH; int n = li >> 6, k = li & 63;
                       v = (k < 40) ? cv(Wih, n * 40 + k) : (u16)0; }
  else if (i < OBIH) v = cv(Whh, i - OWHH);
  else if (i < OBHH) v = cv(bih, i - OBIH);
  else if (i < ODW)  v = cv(bhh, i - OBHH);
  else if (i < ODB)  v = cv(dW,  i - ODW);
  else               v = cv(db_, i - ODB);
  dst[i] = v;
}

__global__ __launch_bounds__(NTHR, 2)
void odernn_kernel(const void* __restrict__ s_in, const void* __restrict__ a_in,
                   const void* __restrict__ t_in, void* __restrict__ out,
                   const void* __restrict__ ws){
  __shared__ alignas(16) u16 h_sh[2][BB][HP];
  __shared__ alignas(16) u16 rh_sh[BB][HP];
  __shared__ alignas(16) u16 x_sh[BB][XP];
  __shared__ float t_sh[BB];

  const int flag = *(const int*)ws;
  const u16* pk  = (const u16*)ws + 8;

  const int tid  = threadIdx.x;
  const int w    = tid >> 6;
  const int lane = tid & 63;
  const int q    = lane >> 4;
  const int m16  = lane & 15;
  const int col  = (w << 4) | m16;
  const int row4 = q << 2;
  const int b0   = blockIdx.x * BB;
  const int aoff = m16 * HP + q * 8;

  for (int i = tid; i < 2*BB*HP; i += NTHR) (&h_sh[0][0][0])[i] = 0;
  for (int i = tid; i < BB*XP;   i += NTHR) (&x_sh[0][0])[i]   = 0;
  if (tid < BB){
    size_t idx = (size_t)(b0 + tid) * TT;
    float tv; if (flag) tv = ((const float*)t_in)[idx]; else tv = bf2f(((const u16*)t_in)[idx]);
    t_sh[tid] = tv;
  }

  const u16* WrP = pk + OW_R; const u16* WzP = pk + OW_Z; const u16* WhP = pk + OW_H;
  const u16* Wsrc[6] = { WrP, WzP, WhP, WrP + OFF2, WzP + OFF2, WhP + OFF2 };
  short8 fw[6][4];
  float fwl[6], fb[6];
#pragma unroll
  for (int m = 0; m < 6; ++m){
#pragma unroll
    for (int ks = 0; ks < 4; ++ks){
      short8 v;
#pragma unroll
      for (int j = 0; j < 8; ++j)
        v[j] = (short)Wsrc[m][(ks*32 + q*8 + j)*HH + col];
      fw[m][ks] = v;
    }
    fwl[m] = bf2f(Wsrc[m][128*HH + col]);
  }
  fb[0] = bf2f(pk[OB_R + col]);      fb[1] = bf2f(pk[OB_Z + col]);      fb[2] = bf2f(pk[OB_H + col]);
  fb[3] = bf2f(pk[OB_R + HH + col]); fb[4] = bf2f(pk[OB_Z + HH + col]); fb[5] = bf2f(pk[OB_H + HH + col]);
  const float ftw0 = bf2f(pk[OTW + col]), ftw1 = bf2f(pk[OTW + HH + col]);

  short8 whhf[3][4];
#pragma unroll
  for (int g = 0; g < 3; ++g){
    const u16* base = pk + OWHH + (size_t)(g*HH + col) * HH;
#pragma unroll
    for (int ks = 0; ks < 4; ++ks)
      whhf[g][ks] = *reinterpret_cast<const short8*>(base + ks*32 + q*8);
  }
  const float bs_r = bf2f(pk[OBIH + col])      + bf2f(pk[OBHH + col]);
  const float bs_z = bf2f(pk[OBIH + HH + col]) + bf2f(pk[OBHH + HH + col]);
  const float bi_n = bf2f(pk[OBIH + 2*HH + col]);
  const float bh_n = bf2f(pk[OBHH + 2*HH + col]);
  const float db   = bf2f(pk[ODB + (col & 31)]);

  float hv[4] = {0.f, 0.f, 0.f, 0.f};
  int cur = 0;
  __syncthreads();

  for (int t = 0; t < TT; ++t){
    const u16* h_in = &h_sh[cur][0][0];
    float tt4[4];
#pragma unroll
    for (int r = 0; r < 4; ++r) tt4[r] = t_sh[row4 + r];

    if (w < 2 && t > 0){
      f32x4 oacc = {0.f,0.f,0.f,0.f};
#pragma unroll
      for (int ks = 0; ks < 4; ++ks){
        short8 da  = *reinterpret_cast<const short8*>(h_in + aoff + ks*32);
        short8 dbw = *reinterpret_cast<const short8*>(pk + ODW + col*HH + ks*32 + q*8);
        oacc = __builtin_amdgcn_mfma_f32_16x16x32_bf16(da, dbw, oacc, 0, 0, 0);
      }
#pragma unroll
      for (int r = 0; r < 4; ++r){
        size_t oidx = ((size_t)(b0 + row4 + r)*TT + (t - 1))*DS + col;
        float val = oacc[r] + db;
        if (flag) ((float*)out)[oidx] = val; else ((u16*)out)[oidx] = f2bf(val);
      }
    }

#pragma unroll
    for (int l = 0; l < 2; ++l){
      const u16* hr = &h_sh[cur][0][0];
      u16* hw = &h_sh[cur ^ 1][0][0];
      short8 ha[4];
#pragma unroll
      for (int ks = 0; ks < 4; ++ks)
        ha[ks] = *reinterpret_cast<const short8*>(hr + aoff + ks*32);
      f32x4 racc = {0.f,0.f,0.f,0.f}, zacc = {0.f,0.f,0.f,0.f};
#pragma unroll
      for (int ks = 0; ks < 4; ++ks){
        racc = __builtin_amdgcn_mfma_f32_16x16x32_bf16(ha[ks], fw[3*l+0][ks], racc, 0, 0, 0);
        zacc = __builtin_amdgcn_mfma_f32_16x16x32_bf16(ha[ks], fw[3*l+1][ks], zacc, 0, 0, 0);
      }
      float zv[4];
#pragma unroll
      for (int r = 0; r < 4; ++r){
        float rv = 0.8f * sigm(racc[r] + tt4[r]*fwl[3*l+0] + fb[3*l+0]);
        zv[r]    = 0.4f * sigm(zacc[r] + tt4[r]*fwl[3*l+1] + fb[3*l+1]);
        rh_sh[row4 + r][col] = f2bf(rv * hv[r]);
      }
      if (l == 1){
        { int row = tid >> 5, c = tid & 31;
          size_t sidx = ((size_t)(b0 + row)*TT + t)*DS + c;
          float sv; if (flag) sv = ((const float*)s_in)[sidx]; else sv = bf2f(((const u16*)s_in)[sidx]);
          x_sh[row][c] = f2bf(sv); }
        if (tid < BB*DA){ int row = tid >> 3, c = tid & 7;
          size_t aidx = ((size_t)(b0 + row)*TT + t)*DA + c;
          float av; if (flag) av = ((const float*)a_in)[aidx]; else av = bf2f(((const u16*)a_in)[aidx]);
          x_sh[row][DS + c] = f2bf(av); }
      }
      __syncthreads();
      short8 ua[4];
#pragma unroll
      for (int ks = 0; ks < 4; ++ks)
        ua[ks] = *reinterpret_cast<const short8*>(&rh_sh[0][0] + aoff + ks*32);
      f32x4 uacc = {0.f,0.f,0.f,0.f};
#pragma unroll
      for (int ks = 0; ks < 4; ++ks)
        uacc = __builtin_amdgcn_mfma_f32_16x16x32_bf16(ua[ks], fw[3*l+2][ks], uacc, 0, 0, 0);
      const float ftwl = l ? ftw1 : ftw0;
#pragma unroll
      for (int r = 0; r < 4; ++r){
        float u   = tanh_(uacc[r] + tt4[r]*fwl[3*l+2] + fb[3*l+2]);
        float phi = tanh_(ftwl * tt4[r]);
        hv[r] = scrub(hv[r] + phi * zv[r] * (u - hv[r]));
        hw[(row4 + r)*HP + col] = f2bf(hv[r]);
      }
      __syncthreads();
      cur ^= 1;
    }

    {
      const u16* hg = &h_sh[cur][0][0];
      u16* hw = &h_sh[cur ^ 1][0][0];
#pragma unroll
      for (int r = 0; r < 4; ++r){
        size_t hidx = HIDOFF + ((size_t)(b0 + row4 + r)*TT + t)*HH + col;
        if (flag) ((float*)out)[hidx] = hv[r]; else ((u16*)out)[hidx] = f2bf(hv[r]);
      }
      if (tid < BB && t + 1 < TT){
        size_t idx = (size_t)(b0 + tid)*TT + t + 1;
        float tv; if (flag) tv = ((const float*)t_in)[idx]; else tv = bf2f(((const u16*)t_in)[idx]);
        t_sh[tid] = tv;
      }

      short8 xa[2];
#pragma unroll
      for (int ks = 0; ks < 2; ++ks)
        xa[ks] = *reinterpret_cast<const short8*>(&x_sh[0][0] + m16*XP + ks*32 + q*8);
      f32x4 ar = {0.f,0.f,0.f,0.f}, az = {0.f,0.f,0.f,0.f};
      f32x4 agin = {0.f,0.f,0.f,0.f}, aghn = {0.f,0.f,0.f,0.f};
      const u16* wr_ih = pk + OWIH + (size_t)col*64;
      const u16* wz_ih = pk + OWIH + (size_t)(HH + col)*64;
      const u16* wn_ih = pk + OWIH + (size_t)(2*HH + col)*64;
#pragma unroll
      for (int ks = 0; ks < 2; ++ks){
        const int kb = ks*32 + q*8;
        ar   = __builtin_amdgcn_mfma_f32_16x16x32_bf16(xa[ks], *reinterpret_cast<const short8*>(wr_ih + kb), ar,   0,0,0);
        az   = __builtin_amdgcn_mfma_f32_16x16x32_bf16(xa[ks], *reinterpret_cast<const short8*>(wz_ih + kb), az,   0,0,0);
        agin = __builtin_amdgcn_mfma_f32_16x16x32_bf16(xa[ks], *reinterpret_cast<const short8*>(wn_ih + kb), agin, 0,0,0);
      }
      short8 hgf[4];
#pragma unroll
      for (int ks = 0; ks < 4; ++ks)
        hgf[ks] = *reinterpret_cast<const short8*>(hg + aoff + ks*32);
#pragma unroll
      for (int ks = 0; ks < 4; ++ks){
        ar   = __builtin_amdgcn_mfma_f32_16x16x32_bf16(hgf[ks], whhf[0][ks], ar,   0,0,0);
        az   = __builtin_amdgcn_mfma_f32_16x16x32_bf16(hgf[ks], whhf[1][ks], az,   0,0,0);
        aghn = __builtin_amdgcn_mfma_f32_16x16x32_bf16(hgf[ks], whhf[2][ks], aghn, 0,0,0);
      }
#pragma unroll
      for (int r = 0; r < 4; ++r){
        float gr = sigm(ar[r] + bs_r);
        float gz = sigm(az[r] + bs_z);
        float gn = tanh_(agin[r] + bi_n + gr*(aghn[r] + bh_n));
        hv[r] = scrub((1.f - gz)*gn + gz*hv[r]);
        hw[(row4 + r)*HP + col] = f2bf(hv[r]);
      }
      __syncthreads();
      cur ^= 1;
    }
  }

  if (w < 2){
    const u16* h_in = &h_sh[cur][0][0];
    f32x4 oacc = {0.f,0.f,0.f,0.f};
#pragma unroll
    for (int ks = 0; ks < 4; ++ks){
      short8 da  = *reinterpret_cast<const short8*>(h_in + aoff + ks*32);
      short8 dbw = *reinterpret_cast<const short8*>(pk + ODW + col*HH + ks*32 + q*8);
      oacc = __builtin_amdgcn_mfma_f32_16x16x32_bf16(da, dbw, oacc, 0, 0, 0);
    }
#pragma unroll
    for (int r = 0; r < 4; ++r){
      size_t oidx = ((size_t)(b0 + row4 + r)*TT + (TT - 1))*DS + col;
      float val = oacc[r] + db;
      if (flag) ((float*)out)[oidx] = val; else ((u16*)out)[oidx] = f2bf(val);
    }
  }
}

extern "C" void kernel_launch(void* const* d_in, const int* in_sizes, int n_in,
                              void* d_out, int out_size, void* d_ws, size_t ws_size,
                              hipStream_t stream){
  detect_kernel<<<1, 64, 0, stream>>>(d_in[2], (int*)d_ws);
  conv_kernel<<<(NPK + 255)/256, 256, 0, stream>>>(d_in[3], d_in[5], d_in[7],
                                                   d_in[4], d_in[6], d_in[8],
                                                   d_in[9], d_in[10], d_in[11],
                                                   d_in[12], d_in[13], d_in[14],
                                                   d_in[15], d_ws);
  odernn_kernel<<<dim3(NB/BB), dim3(NTHR), 0, stream>>>(
      d_in[0], d_in[1], d_in[2], d_out, d_ws);
}